// Round 2
// baseline (5612.815 us; speedup 1.0000x reference)
//
#include <hip/hip_runtime.h>

typedef _Float16 f16;
typedef _Float16 f16x4v __attribute__((ext_vector_type(4)));
typedef _Float16 f16x8  __attribute__((ext_vector_type(8)));
typedef float    f32x4  __attribute__((ext_vector_type(4)));
typedef unsigned long long u64;
typedef unsigned int u32;

#define NB 32
#define NT 512
#define NF 512
#define NH 512
#define NG 2048   // 4*NH gate columns

// workspace layout (bytes)
static const size_t XH_OFF   = 0;
static const size_t XH_BYTES = (size_t)NB*NT*NF*2;        // 16 MiB fp16 x
static const size_t WT_OFF   = XH_OFF + XH_BYTES;
static const size_t WT_BYTES = (size_t)2*NG*1024*2;       //  8 MiB Wt[dir][col][k] fp16
static const size_t GX_OFF   = WT_OFF + WT_BYTES;
static const size_t GX_BYTES = (size_t)2*NB*NT*NG*2;      // 128 MiB gx[dir][b*t][col] fp16
static const size_t HB_OFF   = GX_OFF + GX_BYTES;
static const size_t HB_BYTES = (size_t)2*2*NB*NH*2;       // 128 KiB h exchange [par][dir][b][k]
static const size_t CNT_OFF  = HB_OFF + HB_BYTES;
static const size_t CNT_BYTES= 256;

__device__ __forceinline__ float sigf(float x){ return 1.0f/(1.0f+__expf(-x)); }
__device__ __forceinline__ float tanh_f(float x){ return 1.0f - 2.0f/(__expf(2.0f*x)+1.0f); }

__global__ void k_zero(float4* o, size_t no, uint4* z, size_t nz) {
  size_t i = (size_t)blockIdx.x*blockDim.x + threadIdx.x;
  size_t st = (size_t)gridDim.x*blockDim.x;
  float4 fz = make_float4(0.f,0.f,0.f,0.f);
  uint4  uz = make_uint4(0u,0u,0u,0u);
  for (size_t j=i; j<no; j+=st) o[j]=fz;
  for (size_t j=i; j<nz; j+=st) z[j]=uz;
}

__global__ void k_cvt(const float* __restrict__ x, f16* __restrict__ xh) {
  size_t i = ((size_t)blockIdx.x*blockDim.x + threadIdx.x)*4;
  float4 v = *(const float4*)(x+i);
  f16x4v h; h[0]=(f16)v.x; h[1]=(f16)v.y; h[2]=(f16)v.z; h[3]=(f16)v.w;
  *(f16x4v*)(xh+i) = h;
}

// W [1024][2048] f32 -> Wt[dir][col 2048][k 1024] fp16 (tiled transpose)
__global__ void k_tw(const float* __restrict__ Wfw, const float* __restrict__ Wbw,
                     f16* __restrict__ Wt) {
  __shared__ f16 tile[32][33];
  int b = blockIdx.x;
  int dir = b >> 11; int rem = b & 2047;
  int kt = rem >> 6, ct = rem & 63;
  const float* W = dir ? Wbw : Wfw;
  int tx = threadIdx.x & 31, ty0 = threadIdx.x >> 5;
  int k0 = kt*32, c0 = ct*32;
  for (int yy=ty0; yy<32; yy+=8)
    tile[yy][tx] = (f16)W[(size_t)(k0+yy)*2048 + c0 + tx];
  __syncthreads();
  f16* Wd = Wt + (size_t)dir*2048*1024;
  for (int yy=ty0; yy<32; yy+=8)
    Wd[(size_t)(c0+yy)*1024 + k0 + tx] = tile[tx][yy];
}

// gx[dir][row 16384][col 2048] = xh[row][k0..512) @ Wt[dir][col][k0..512) + bias[col]
// 128x128 tile, BK=32, 4 waves (2x2 of 64x64), global_load_lds + 16B XOR swizzle.
__global__ __launch_bounds__(256) void k_gx(const f16* __restrict__ xh,
    const f16* __restrict__ Wt, const float* __restrict__ bfw,
    const float* __restrict__ bbw, f16* __restrict__ gx)
{
  __shared__ f16 As[128*32];
  __shared__ f16 Bs[128*32];
  int bm0 = blockIdx.x * 128;
  int bn0 = blockIdx.y * 128;
  int dir = blockIdx.z;
  const f16* Wd = Wt + (size_t)dir*NG*1024;
  const float* bias = dir ? bbw : bfw;
  f16* gxd = gx + (size_t)dir*NB*NT*NG;

  int tid = threadIdx.x;
  int w = tid>>6, lane = tid&63;
  int cc = lane&15, q = lane>>4;
  int wm = w>>1, wn = w&1;

  f32x4 acc[4][4];
#pragma unroll
  for (int i=0;i<4;++i)
#pragma unroll
    for (int j=0;j<4;++j) acc[i][j] = (f32x4){0.f,0.f,0.f,0.f};

  for (int kt=0; kt<16; ++kt) {
    int k0 = kt*32;
#pragma unroll
    for (int c=0;c<2;++c) {
      int ch = w*2 + c;
      int row = ch*16 + (lane>>2);
      int cph = (lane&3)*16;
      int clg = cph ^ (((row>>1)&3)<<4);
      const f16* ga = xh + (size_t)(bm0+row)*NF   + k0 + (clg>>1);
      const f16* gb = Wd + (size_t)(bn0+row)*1024 + k0 + (clg>>1);
      __builtin_amdgcn_global_load_lds(
          (const __attribute__((address_space(1))) u32*)ga,
          (__attribute__((address_space(3))) u32*)(As + ch*512), 16, 0, 0);
      __builtin_amdgcn_global_load_lds(
          (const __attribute__((address_space(1))) u32*)gb,
          (__attribute__((address_space(3))) u32*)(Bs + ch*512), 16, 0, 0);
    }
    __syncthreads();   // waits vmcnt(0): LDS writes landed

    f16x8 av[4], bv[4];
#pragma unroll
    for (int mi=0;mi<4;++mi) {
      int r = wm*64 + mi*16 + cc;
      int sw = ((r>>1)&3)<<4;
      u64 lo = *(const u64*)&As[r*32 + ((((q*8)   ) ^ sw)>>1)];
      u64 hi = *(const u64*)&As[r*32 + ((((q*8)+32) ^ sw)>>1)];
      f16x4v l4 = __builtin_bit_cast(f16x4v, lo);
      f16x4v h4 = __builtin_bit_cast(f16x4v, hi);
      f16x8 a; a[0]=l4[0];a[1]=l4[1];a[2]=l4[2];a[3]=l4[3];
      a[4]=h4[0];a[5]=h4[1];a[6]=h4[2];a[7]=h4[3];
      av[mi]=a;
    }
#pragma unroll
    for (int ni=0;ni<4;++ni) {
      int r = wn*64 + ni*16 + cc;
      int sw = ((r>>1)&3)<<4;
      u64 lo = *(const u64*)&Bs[r*32 + ((((q*8)   ) ^ sw)>>1)];
      u64 hi = *(const u64*)&Bs[r*32 + ((((q*8)+32) ^ sw)>>1)];
      f16x4v l4 = __builtin_bit_cast(f16x4v, lo);
      f16x4v h4 = __builtin_bit_cast(f16x4v, hi);
      f16x8 a; a[0]=l4[0];a[1]=l4[1];a[2]=l4[2];a[3]=l4[3];
      a[4]=h4[0];a[5]=h4[1];a[6]=h4[2];a[7]=h4[3];
      bv[ni]=a;
    }
#pragma unroll
    for (int mi=0;mi<4;++mi)
#pragma unroll
      for (int ni=0;ni<4;++ni)
        acc[mi][ni] = __builtin_amdgcn_mfma_f32_16x16x32_f16(av[mi], bv[ni], acc[mi][ni], 0,0,0);
    __syncthreads();
  }

#pragma unroll
  for (int ni=0;ni<4;++ni) {
    int col = bn0 + wn*64 + ni*16 + cc;
    float bvl = bias[col];
#pragma unroll
    for (int mi=0;mi<4;++mi)
#pragma unroll
      for (int rr=0;rr<4;++rr) {
        int row = bm0 + wm*64 + mi*16 + q*4 + rr;
        gxd[(size_t)row*NG + col] = (f16)(acc[mi][ni][rr] + bvl);
      }
  }
}

// Persistent recurrence. 16 blocks: dir = bid>>3, rank = bid&7.
// Block owns h-cols [rank*64, rank*64+64) for ALL 32 batches; wave w owns 16 cols.
// Full K=512 (h half) per wave -> no LDS reduce; W_h in 256 VGPRs/lane.
__global__ __launch_bounds__(256, 1) void k_rnn(
    const f16* __restrict__ gx, const f16* __restrict__ Wt,
    u64* hbuf, u32* cnt, const int* __restrict__ seqlen,
    float* __restrict__ out)
{
  int bid = blockIdx.x;
  int dir = bid >> 3, rank = bid & 7;
  int tid = threadIdx.x;
  int w = tid>>6, lane = tid&63, cc = lane&15, q = lane>>4;
  int ncol0 = rank*64 + w*16;

  // Persistent W_h fragments: col = g*512 + ncol0 + cc, k = 512 + kk*32 + q*4 (+16)
  f16x8 Wf[16][4];
  {
    const f16* Wd = Wt + (size_t)dir*NG*1024;
#pragma unroll
    for (int kk=0;kk<16;++kk)
#pragma unroll
      for (int g=0;g<4;++g) {
        const f16* pp = Wd + (size_t)(g*NH + ncol0 + cc)*1024 + 512 + kk*32 + q*4;
        f16x4v lo = *(const f16x4v*)pp;
        f16x4v hi = *(const f16x4v*)(pp+16);
        f16x8 a; a[0]=lo[0];a[1]=lo[1];a[2]=lo[2];a[3]=lo[3];
        a[4]=hi[0];a[5]=hi[1];a[6]=hi[2];a[7]=hi[3];
        Wf[kk][g] = a;
      }
  }

  int Lr[2][4];
#pragma unroll
  for (int mi=0;mi<2;++mi)
#pragma unroll
    for (int rr=0;rr<4;++rr)
      Lr[mi][rr] = seqlen[mi*16 + q*4 + rr];

  float cst[2][4], hst[2][4];
#pragma unroll
  for (int mi=0;mi<2;++mi)
#pragma unroll
    for (int rr=0;rr<4;++rr) { cst[mi][rr]=0.f; hst[mi][rr]=0.f; }

  u32* mycnt = cnt + dir*32;
  const f16* gxd = gx + (size_t)dir*NB*NT*NG;
  float* outd = out + dir*NH;

  for (int s = 0; s < NT; ++s) {
    int p = s & 1;

    // gx prefetch (no dependence on barrier) — hides under the spin wait
    f16 gxr[4][2][4];
#pragma unroll
    for (int mi=0;mi<2;++mi)
#pragma unroll
      for (int rr=0;rr<4;++rr) {
        int b = mi*16 + q*4 + rr;
        int u = (dir==0) ? s : (Lr[mi][rr]-1-s);
        u = u < 0 ? 0 : u;
        const f16* gp = gxd + ((size_t)b*NT + u)*NG + ncol0 + cc;
#pragma unroll
        for (int g=0;g<4;++g) gxr[g][mi][rr] = gp[(size_t)g*NH];
      }

    if (s > 0) {
      if (tid == 0) {
        u32 tgt = 8u*(u32)s;
        while (__hip_atomic_load(mycnt, __ATOMIC_ACQUIRE, __HIP_MEMORY_SCOPE_AGENT) < tgt)
          __builtin_amdgcn_s_sleep(1);
      }
      __syncthreads();
    }

    f32x4 acc[4][2];
#pragma unroll
    for (int g=0;g<4;++g)
#pragma unroll
      for (int mi=0;mi<2;++mi) acc[g][mi] = (f32x4){0.f,0.f,0.f,0.f};

    const u64* hb = (const u64*)hbuf + ((size_t)(p*2+dir)*NB)*(NH/4);
#pragma unroll
    for (int kk=0;kk<16;++kk) {
      f16x8 af[2];
#pragma unroll
      for (int mi=0;mi<2;++mi) {
        int b = mi*16 + cc;
        const u64* hp = hb + (size_t)b*(NH/4) + kk*8 + q;
        u64 lo = __hip_atomic_load(hp,   __ATOMIC_RELAXED, __HIP_MEMORY_SCOPE_AGENT);
        u64 hi = __hip_atomic_load(hp+4, __ATOMIC_RELAXED, __HIP_MEMORY_SCOPE_AGENT);
        f16x4v l4 = __builtin_bit_cast(f16x4v, lo);
        f16x4v h4 = __builtin_bit_cast(f16x4v, hi);
        f16x8 a; a[0]=l4[0];a[1]=l4[1];a[2]=l4[2];a[3]=l4[3];
        a[4]=h4[0];a[5]=h4[1];a[6]=h4[2];a[7]=h4[3];
        af[mi]=a;
      }
#pragma unroll
      for (int g=0;g<4;++g) {
        acc[g][0] = __builtin_amdgcn_mfma_f32_16x16x32_f16(af[0], Wf[kk][g], acc[g][0], 0,0,0);
        acc[g][1] = __builtin_amdgcn_mfma_f32_16x16x32_f16(af[1], Wf[kk][g], acc[g][1], 0,0,0);
      }
    }

    u32* hw = (u32*)hbuf + ((size_t)((p^1)*2+dir)*NB)*(NH/2);
#pragma unroll
    for (int mi=0;mi<2;++mi)
#pragma unroll
      for (int rr=0;rr<4;++rr) {
        int b = mi*16 + q*4 + rr;
        float gi = acc[0][mi][rr] + (float)gxr[0][mi][rr];
        float gj = acc[1][mi][rr] + (float)gxr[1][mi][rr];
        float gf = acc[2][mi][rr] + (float)gxr[2][mi][rr];
        float go = acc[3][mi][rr] + (float)gxr[3][mi][rr];
        int L = Lr[mi][rr];
        float hv = hst[mi][rr];
        if (s < L) {
          float cn = sigf(gf + 1.0f)*cst[mi][rr] + sigf(gi)*tanh_f(gj);
          float hn = sigf(go)*tanh_f(cn);
          cst[mi][rr] = cn; hst[mi][rr] = hn; hv = hn;
          int u = (dir==0) ? s : (L-1-s);
          outd[((size_t)b*NT + u)*(2*NH) + ncol0 + cc] = hn;
        }
        float hv2 = __shfl_down(hv, 1);
        if (!(cc & 1)) {
          f16 h0 = (f16)hv, h1 = (f16)hv2;
          u32 pk = (u32)__builtin_bit_cast(unsigned short, h0)
                 | ((u32)__builtin_bit_cast(unsigned short, h1) << 16);
          __hip_atomic_store(hw + (size_t)b*(NH/2) + ((ncol0+cc)>>1), pk,
                             __ATOMIC_RELAXED, __HIP_MEMORY_SCOPE_AGENT);
        }
      }
    __syncthreads();   // drains stores (vmcnt 0) before the release RMW
    if (tid == 0)
      __hip_atomic_fetch_add(mycnt, 1u, __ATOMIC_ACQ_REL, __HIP_MEMORY_SCOPE_AGENT);
  }
}

extern "C" void kernel_launch(void* const* d_in, const int* in_sizes, int n_in,
                              void* d_out, int out_size, void* d_ws, size_t ws_size,
                              hipStream_t stream) {
  (void)in_sizes; (void)n_in; (void)out_size; (void)ws_size;
  const float* x      = (const float*)d_in[0];
  const int*   seqlen = (const int*)  d_in[1];
  const float* Wfw    = (const float*)d_in[2];
  const float* bfw    = (const float*)d_in[3];
  const float* Wbw    = (const float*)d_in[4];
  const float* bbw    = (const float*)d_in[5];
  float* out = (float*)d_out;
  unsigned char* ws = (unsigned char*)d_ws;

  f16* xh   = (f16*)(ws + XH_OFF);
  f16* Wt   = (f16*)(ws + WT_OFF);
  f16* gx   = (f16*)(ws + GX_OFF);
  u64* hbuf = (u64*)(ws + HB_OFF);
  u32* cnt  = (u32*)(ws + CNT_OFF);

  size_t no = (size_t)NB*NT*2*NH/4;            // float4 count of d_out
  size_t nz = (HB_BYTES + CNT_BYTES)/16;       // uint4 count of hbuf + counters
  k_zero<<<dim3(2048), dim3(256), 0, stream>>>((float4*)d_out, no,
                                               (uint4*)(ws + HB_OFF), nz);
  k_cvt<<<dim3((NB*NT*NF/4)/256), dim3(256), 0, stream>>>(x, xh);
  k_tw <<<dim3(4096), dim3(256), 0, stream>>>(Wfw, Wbw, Wt);
  k_gx <<<dim3(128, 16, 2), dim3(256), 0, stream>>>(xh, Wt, bfw, bbw, gx);
  k_rnn<<<dim3(16), dim3(256), 0, stream>>>(gx, Wt, hbuf, cnt, seqlen, out);
}

// Round 3
// 5242.361 us; speedup vs baseline: 1.0707x; 1.0707x over previous
//
#include <hip/hip_runtime.h>

typedef _Float16 f16;
typedef _Float16 f16x4v __attribute__((ext_vector_type(4)));
typedef _Float16 f16x8  __attribute__((ext_vector_type(8)));
typedef float    f32x4  __attribute__((ext_vector_type(4)));
typedef unsigned long long u64;
typedef unsigned int u32;

#define NB 32
#define NT 512
#define NF 512
#define NH 512
#define NG 2048   // 4*NH gate columns

// workspace layout (bytes)
static const size_t XH_OFF   = 0;
static const size_t XH_BYTES = (size_t)NB*NT*NF*2;        // 16 MiB fp16 x
static const size_t WT_OFF   = XH_OFF + XH_BYTES;
static const size_t WT_BYTES = (size_t)2*NG*1024*2;       //  8 MiB Wt[dir][col][k] fp16
static const size_t GX_OFF   = WT_OFF + WT_BYTES;
static const size_t GX_BYTES = (size_t)2*NB*NT*NG*2;      // 128 MiB gx[dir][b*t][col] fp16
static const size_t HB_OFF   = GX_OFF + GX_BYTES;
static const size_t HB_BYTES = (size_t)2*2*NB*NH*2;       // 128 KiB h exchange [par][dir][b][k]
static const size_t CNT_OFF  = HB_OFF + HB_BYTES;
static const size_t CNT_BYTES= 16*128;                    // 16 flag slots, 128B padded

__device__ __forceinline__ float sigf(float x){ return 1.0f/(1.0f+__expf(-x)); }
__device__ __forceinline__ float tanh_f(float x){ return 1.0f - 2.0f/(__expf(2.0f*x)+1.0f); }

__global__ void k_zero(float4* o, size_t no, uint4* z, size_t nz) {
  size_t i = (size_t)blockIdx.x*blockDim.x + threadIdx.x;
  size_t st = (size_t)gridDim.x*blockDim.x;
  float4 fz = make_float4(0.f,0.f,0.f,0.f);
  uint4  uz = make_uint4(0u,0u,0u,0u);
  for (size_t j=i; j<no; j+=st) o[j]=fz;
  for (size_t j=i; j<nz; j+=st) z[j]=uz;
}

__global__ void k_cvt(const float* __restrict__ x, f16* __restrict__ xh) {
  size_t i = ((size_t)blockIdx.x*blockDim.x + threadIdx.x)*4;
  float4 v = *(const float4*)(x+i);
  f16x4v h; h[0]=(f16)v.x; h[1]=(f16)v.y; h[2]=(f16)v.z; h[3]=(f16)v.w;
  *(f16x4v*)(xh+i) = h;
}

// W [1024][2048] f32 -> Wt[dir][col 2048][k 1024] fp16 (tiled transpose)
__global__ void k_tw(const float* __restrict__ Wfw, const float* __restrict__ Wbw,
                     f16* __restrict__ Wt) {
  __shared__ f16 tile[32][33];
  int b = blockIdx.x;
  int dir = b >> 11; int rem = b & 2047;
  int kt = rem >> 6, ct = rem & 63;
  const float* W = dir ? Wbw : Wfw;
  int tx = threadIdx.x & 31, ty0 = threadIdx.x >> 5;
  int k0 = kt*32, c0 = ct*32;
  for (int yy=ty0; yy<32; yy+=8)
    tile[yy][tx] = (f16)W[(size_t)(k0+yy)*2048 + c0 + tx];
  __syncthreads();
  f16* Wd = Wt + (size_t)dir*2048*1024;
  for (int yy=ty0; yy<32; yy+=8)
    Wd[(size_t)(c0+yy)*1024 + k0 + tx] = tile[tx][yy];
}

// gx[dir][row 16384][col 2048] = xh[row][k0..512) @ Wt[dir][col][k0..512) + bias[col]
// 128x128 tile, BK=32, 4 waves (2x2 of 64x64), global_load_lds + 16B XOR swizzle.
__global__ __launch_bounds__(256) void k_gx(const f16* __restrict__ xh,
    const f16* __restrict__ Wt, const float* __restrict__ bfw,
    const float* __restrict__ bbw, f16* __restrict__ gx)
{
  __shared__ f16 As[128*32];
  __shared__ f16 Bs[128*32];
  int bm0 = blockIdx.x * 128;
  int bn0 = blockIdx.y * 128;
  int dir = blockIdx.z;
  const f16* Wd = Wt + (size_t)dir*NG*1024;
  const float* bias = dir ? bbw : bfw;
  f16* gxd = gx + (size_t)dir*NB*NT*NG;

  int tid = threadIdx.x;
  int w = tid>>6, lane = tid&63;
  int cc = lane&15, q = lane>>4;
  int wm = w>>1, wn = w&1;

  f32x4 acc[4][4];
#pragma unroll
  for (int i=0;i<4;++i)
#pragma unroll
    for (int j=0;j<4;++j) acc[i][j] = (f32x4){0.f,0.f,0.f,0.f};

  for (int kt=0; kt<16; ++kt) {
    int k0 = kt*32;
#pragma unroll
    for (int c=0;c<2;++c) {
      int ch = w*2 + c;
      int row = ch*16 + (lane>>2);
      int cph = (lane&3)*16;
      int clg = cph ^ (((row>>1)&3)<<4);
      const f16* ga = xh + (size_t)(bm0+row)*NF   + k0 + (clg>>1);
      const f16* gb = Wd + (size_t)(bn0+row)*1024 + k0 + (clg>>1);
      __builtin_amdgcn_global_load_lds(
          (const __attribute__((address_space(1))) u32*)ga,
          (__attribute__((address_space(3))) u32*)(As + ch*512), 16, 0, 0);
      __builtin_amdgcn_global_load_lds(
          (const __attribute__((address_space(1))) u32*)gb,
          (__attribute__((address_space(3))) u32*)(Bs + ch*512), 16, 0, 0);
    }
    __syncthreads();   // waits vmcnt(0): LDS writes landed

    f16x8 av[4], bv[4];
#pragma unroll
    for (int mi=0;mi<4;++mi) {
      int r = wm*64 + mi*16 + cc;
      int sw = ((r>>1)&3)<<4;
      u64 lo = *(const u64*)&As[r*32 + ((((q*8)   ) ^ sw)>>1)];
      u64 hi = *(const u64*)&As[r*32 + ((((q*8)+32) ^ sw)>>1)];
      f16x4v l4 = __builtin_bit_cast(f16x4v, lo);
      f16x4v h4 = __builtin_bit_cast(f16x4v, hi);
      f16x8 a; a[0]=l4[0];a[1]=l4[1];a[2]=l4[2];a[3]=l4[3];
      a[4]=h4[0];a[5]=h4[1];a[6]=h4[2];a[7]=h4[3];
      av[mi]=a;
    }
#pragma unroll
    for (int ni=0;ni<4;++ni) {
      int r = wn*64 + ni*16 + cc;
      int sw = ((r>>1)&3)<<4;
      u64 lo = *(const u64*)&Bs[r*32 + ((((q*8)   ) ^ sw)>>1)];
      u64 hi = *(const u64*)&Bs[r*32 + ((((q*8)+32) ^ sw)>>1)];
      f16x4v l4 = __builtin_bit_cast(f16x4v, lo);
      f16x4v h4 = __builtin_bit_cast(f16x4v, hi);
      f16x8 a; a[0]=l4[0];a[1]=l4[1];a[2]=l4[2];a[3]=l4[3];
      a[4]=h4[0];a[5]=h4[1];a[6]=h4[2];a[7]=h4[3];
      bv[ni]=a;
    }
#pragma unroll
    for (int mi=0;mi<4;++mi)
#pragma unroll
      for (int ni=0;ni<4;++ni)
        acc[mi][ni] = __builtin_amdgcn_mfma_f32_16x16x32_f16(av[mi], bv[ni], acc[mi][ni], 0,0,0);
    __syncthreads();
  }

#pragma unroll
  for (int ni=0;ni<4;++ni) {
    int col = bn0 + wn*64 + ni*16 + cc;
    float bvl = bias[col];
#pragma unroll
    for (int mi=0;mi<4;++mi)
#pragma unroll
      for (int rr=0;rr<4;++rr) {
        int row = bm0 + wm*64 + mi*16 + q*4 + rr;
        gxd[(size_t)row*NG + col] = (f16)(acc[mi][ni][rr] + bvl);
      }
  }
}

// Persistent recurrence. 16 blocks: dir = bid>>3, rank = bid&7.
// Block owns h-cols [rank*64, rank*64+64) for ALL 32 batches; wave w owns 16 cols.
// Sync: per-producer relaxed flag slots + per-wave polling + one acquire fence.
// NO acq_rel/release agent atomics anywhere (they lower to buffer_wbl2 = full L2
// writeback walk per step — the round-1/2 10.5us/step invariant).
__global__ __launch_bounds__(256, 1) void k_rnn(
    const f16* __restrict__ gx, const f16* __restrict__ Wt,
    u64* hbuf, u32* cnt, const int* __restrict__ seqlen,
    float* __restrict__ out)
{
  int bid = blockIdx.x;
  int dir = bid >> 3, rank = bid & 7;
  int tid = threadIdx.x;
  int w = tid>>6, lane = tid&63, cc = lane&15, q = lane>>4;
  int ncol0 = rank*64 + w*16;

  // Persistent W_h fragments: col = g*512 + ncol0 + cc, k = 512 + kk*32 + q*4 (+16)
  f16x8 Wf[16][4];
  {
    const f16* Wd = Wt + (size_t)dir*NG*1024;
#pragma unroll
    for (int kk=0;kk<16;++kk)
#pragma unroll
      for (int g=0;g<4;++g) {
        const f16* pp = Wd + (size_t)(g*NH + ncol0 + cc)*1024 + 512 + kk*32 + q*4;
        f16x4v lo = *(const f16x4v*)pp;
        f16x4v hi = *(const f16x4v*)(pp+16);
        f16x8 a; a[0]=lo[0];a[1]=lo[1];a[2]=lo[2];a[3]=lo[3];
        a[4]=hi[0];a[5]=hi[1];a[6]=hi[2];a[7]=hi[3];
        Wf[kk][g] = a;
      }
  }

  int Lr[2][4];
#pragma unroll
  for (int mi=0;mi<2;++mi)
#pragma unroll
    for (int rr=0;rr<4;++rr)
      Lr[mi][rr] = seqlen[mi*16 + q*4 + rr];

  float cst[2][4], hst[2][4];
#pragma unroll
  for (int mi=0;mi<2;++mi)
#pragma unroll
    for (int rr=0;rr<4;++rr) { cst[mi][rr]=0.f; hst[mi][rr]=0.f; }

  u32* flg   = cnt + (size_t)dir*8*32;     // 8 slots, 128B apart
  u32* myflg = cnt + (size_t)(dir*8+rank)*32;
  const f16* gxd = gx + (size_t)dir*NB*NT*NG;
  float* outd = out + dir*NH;
  int fl = (lane & 7) * 32;

  for (int s = 0; s < NT; ++s) {
    int p = s & 1;

    // gx prefetch (independent of the flag wait) — hides HBM latency under the spin
    f16 gxr[4][2][4];
#pragma unroll
    for (int mi=0;mi<2;++mi)
#pragma unroll
      for (int rr=0;rr<4;++rr) {
        int b = mi*16 + q*4 + rr;
        int u = (dir==0) ? s : (Lr[mi][rr]-1-s);
        u = u < 0 ? 0 : u;
        const f16* gp = gxd + ((size_t)b*NT + u)*NG + ncol0 + cc;
#pragma unroll
        for (int g=0;g<4;++g) gxr[g][mi][rr] = gp[(size_t)g*NH];
      }

    if (s > 0) {
      // per-wave poll: lanes 0-7 watch the 8 producer flags (relaxed, no buffer_inv)
      u32 tgt = (u32)s;
      for (;;) {
        u32 fv = __hip_atomic_load(flg + fl, __ATOMIC_RELAXED, __HIP_MEMORY_SCOPE_AGENT);
        if (__all(fv >= tgt)) break;
        __builtin_amdgcn_s_sleep(1);
      }
      // one acquire fence per step: orders the h loads after the poll
      __builtin_amdgcn_fence(__ATOMIC_ACQUIRE, "agent");
    }

    f32x4 acc[4][2];
#pragma unroll
    for (int g=0;g<4;++g)
#pragma unroll
      for (int mi=0;mi<2;++mi) acc[g][mi] = (f32x4){0.f,0.f,0.f,0.f};

    const u64* hb = (const u64*)hbuf + ((size_t)(p*2+dir)*NB)*(NH/4);
#pragma unroll
    for (int kk=0;kk<16;++kk) {
      f16x8 af[2];
#pragma unroll
      for (int mi=0;mi<2;++mi) {
        int b = mi*16 + cc;
        const u64* hp = hb + (size_t)b*(NH/4) + kk*8 + q;
        u64 lo = __hip_atomic_load(hp,   __ATOMIC_RELAXED, __HIP_MEMORY_SCOPE_AGENT);
        u64 hi = __hip_atomic_load(hp+4, __ATOMIC_RELAXED, __HIP_MEMORY_SCOPE_AGENT);
        f16x4v l4 = __builtin_bit_cast(f16x4v, lo);
        f16x4v h4 = __builtin_bit_cast(f16x4v, hi);
        f16x8 a; a[0]=l4[0];a[1]=l4[1];a[2]=l4[2];a[3]=l4[3];
        a[4]=h4[0];a[5]=h4[1];a[6]=h4[2];a[7]=h4[3];
        af[mi]=a;
      }
#pragma unroll
      for (int g=0;g<4;++g) {
        acc[g][0] = __builtin_amdgcn_mfma_f32_16x16x32_f16(af[0], Wf[kk][g], acc[g][0], 0,0,0);
        acc[g][1] = __builtin_amdgcn_mfma_f32_16x16x32_f16(af[1], Wf[kk][g], acc[g][1], 0,0,0);
      }
    }

    u32* hw = (u32*)hbuf + ((size_t)((p^1)*2+dir)*NB)*(NH/2);
#pragma unroll
    for (int mi=0;mi<2;++mi)
#pragma unroll
      for (int rr=0;rr<4;++rr) {
        int b = mi*16 + q*4 + rr;
        float gi = acc[0][mi][rr] + (float)gxr[0][mi][rr];
        float gj = acc[1][mi][rr] + (float)gxr[1][mi][rr];
        float gf = acc[2][mi][rr] + (float)gxr[2][mi][rr];
        float go = acc[3][mi][rr] + (float)gxr[3][mi][rr];
        int L = Lr[mi][rr];
        float hv = hst[mi][rr];
        if (s < L) {
          float cn = sigf(gf + 1.0f)*cst[mi][rr] + sigf(gi)*tanh_f(gj);
          float hn = sigf(go)*tanh_f(cn);
          cst[mi][rr] = cn; hst[mi][rr] = hn; hv = hn;
          int u = (dir==0) ? s : (L-1-s);
          outd[((size_t)b*NT + u)*(2*NH) + ncol0 + cc] = hn;
        }
        float hv2 = __shfl_down(hv, 1);
        if (!(cc & 1)) {
          f16 h0 = (f16)hv, h1 = (f16)hv2;
          u32 pk = (u32)__builtin_bit_cast(unsigned short, h0)
                 | ((u32)__builtin_bit_cast(unsigned short, h1) << 16);
          __hip_atomic_store(hw + (size_t)b*(NH/2) + ((ncol0+cc)>>1), pk,
                             __ATOMIC_RELAXED, __HIP_MEMORY_SCOPE_AGENT);
        }
      }
    // barrier drains every wave's vmcnt(0): the sc1 h-stores have completed at the
    // LLC before tid0 publishes the flag (hardware ordering without buffer_wbl2).
    __syncthreads();
    if (tid == 0)
      __hip_atomic_store(myflg, (u32)(s+1), __ATOMIC_RELAXED, __HIP_MEMORY_SCOPE_AGENT);
  }
}

extern "C" void kernel_launch(void* const* d_in, const int* in_sizes, int n_in,
                              void* d_out, int out_size, void* d_ws, size_t ws_size,
                              hipStream_t stream) {
  (void)in_sizes; (void)n_in; (void)out_size; (void)ws_size;
  const float* x      = (const float*)d_in[0];
  const int*   seqlen = (const int*)  d_in[1];
  const float* Wfw    = (const float*)d_in[2];
  const float* bfw    = (const float*)d_in[3];
  const float* Wbw    = (const float*)d_in[4];
  const float* bbw    = (const float*)d_in[5];
  float* out = (float*)d_out;
  unsigned char* ws = (unsigned char*)d_ws;

  f16* xh   = (f16*)(ws + XH_OFF);
  f16* Wt   = (f16*)(ws + WT_OFF);
  f16* gx   = (f16*)(ws + GX_OFF);
  u64* hbuf = (u64*)(ws + HB_OFF);
  u32* cnt  = (u32*)(ws + CNT_OFF);

  size_t no = (size_t)NB*NT*2*NH/4;            // float4 count of d_out
  size_t nz = (HB_BYTES + CNT_BYTES)/16;       // uint4 count of hbuf + flags
  k_zero<<<dim3(2048), dim3(256), 0, stream>>>((float4*)d_out, no,
                                               (uint4*)(ws + HB_OFF), nz);
  k_cvt<<<dim3((NB*NT*NF/4)/256), dim3(256), 0, stream>>>(x, xh);
  k_tw <<<dim3(4096), dim3(256), 0, stream>>>(Wfw, Wbw, Wt);
  k_gx <<<dim3(128, 16, 2), dim3(256), 0, stream>>>(xh, Wt, bfw, bbw, gx);
  k_rnn<<<dim3(16), dim3(256), 0, stream>>>(gx, Wt, hbuf, cnt, seqlen, out);
}